// Round 1
// baseline (479.038 us; speedup 1.0000x reference)
//
#include <hip/hip_runtime.h>
#include <hip/hip_bf16.h>
#include <stdint.h>

#define DM 1024
#define NH 16
#define HD 64
#define SEQ 2048
#define NB 2

typedef __attribute__((ext_vector_type(8)))  __bf16 bf16x8;
typedef __attribute__((ext_vector_type(4)))  __bf16 bf16x4;
typedef __attribute__((ext_vector_type(4)))  float  f32x4;
typedef __attribute__((ext_vector_type(16))) float  f32x16;
typedef __attribute__((ext_vector_type(4)))  unsigned int uint4v;

__device__ __forceinline__ f32x16 mfma32x32(bf16x8 a, bf16x8 b, f32x16 c) {
  return __builtin_amdgcn_mfma_f32_32x32x16_bf16(a, b, c, 0, 0, 0);
}
__device__ __forceinline__ f32x4 mfma16x16(bf16x8 a, bf16x8 b, f32x4 c) {
  return __builtin_amdgcn_mfma_f32_16x16x32_bf16(a, b, c, 0, 0, 0);
}
__device__ __forceinline__ unsigned pkbf(float a, float b) {
  unsigned short ua = __builtin_bit_cast(unsigned short, (__bf16)a);
  unsigned short ub = __builtin_bit_cast(unsigned short, (__bf16)b);
  return (unsigned)ua | ((unsigned)ub << 16);
}
__device__ __forceinline__ f32x16 zero16() {
  f32x16 z;
#pragma unroll
  for (int i = 0; i < 16; i++) z[i] = 0.0f;
  return z;
}

// ---------------- W transpose + bf16 convert: Wt[n][k] = (bf16)W[k][n] ----
__global__ void wconv_kernel(const float* __restrict__ Wq, const float* __restrict__ Wk,
                             const float* __restrict__ Wv, const float* __restrict__ Wo,
                             __bf16* __restrict__ Wt) {
  __shared__ float tile[32][33];
  const int which = blockIdx.z;
  const float* W = (which == 0) ? Wq : (which == 1) ? Wk : (which == 2) ? Wv : Wo;
  __bf16* out = Wt + (size_t)which * DM * DM;
  const int n0 = blockIdx.x * 32, k0 = blockIdx.y * 32;
  const int tx = threadIdx.x & 31, ty = threadIdx.x >> 5;  // ty 0..7
#pragma unroll
  for (int i = 0; i < 4; i++) {
    tile[ty + i * 8][tx] = W[(size_t)(k0 + ty + i * 8) * DM + n0 + tx];
  }
  __syncthreads();
#pragma unroll
  for (int i = 0; i < 4; i++) {
    out[(size_t)(n0 + ty + i * 8) * DM + k0 + tx] = (__bf16)tile[tx][ty + i * 8];
  }
}

// ---------------- GEMM: C[4096,1024] = A[4096,1024] @ B[1024,1024] + bias --
// AMODE 0: A = fp32 row-major (converted to bf16 while staging)
// AMODE 1: A = sum of two fp32 partials in head-major [b,h,l,d] layout
// OMODE 0: bf16 head-major out[b,h,l,d]   (h=col/64, d=col%64)
// OMODE 1: bf16 transposed  out[b,h,d,l]  (V^T for PV fragments)
// OMODE 2: fp32 row-major out (final output)
template <int AMODE, int OMODE>
__global__ __launch_bounds__(256, 2)
void gemm_kernel(const void* __restrict__ Aptr, const void* __restrict__ A2ptr,
                 const __bf16* __restrict__ Bt, const float* __restrict__ bias,
                 void* __restrict__ Out) {
  __shared__ __bf16 Alds[128][40];
  __shared__ __bf16 Blds[128][40];
  const int tid = threadIdx.x;
  const int l = tid & 63, w = tid >> 6;
  const int wm = w >> 1, wn = w & 1;
  const int r0 = blockIdx.x * 128, c0 = blockIdx.y * 128;

  f32x4 acc[4][4];
#pragma unroll
  for (int m = 0; m < 4; m++)
#pragma unroll
    for (int n = 0; n < 4; n++)
#pragma unroll
      for (int r = 0; r < 4; r++) acc[m][n][r] = 0.0f;

  const int ar = tid >> 2;  // 0..63 (two rows per thread: ar, ar+64)
  const int aq = tid & 3;   // 8-float column group
  const int br = tid >> 1;  // 0..127
  const int bh = tid & 1;

  for (int kt = 0; kt < DM / 32; kt++) {
#pragma unroll
    for (int rep = 0; rep < 2; rep++) {
      const int row = ar + rep * 64;
      float fv[8];
      if constexpr (AMODE == 0) {
        const float* src = (const float*)Aptr + (size_t)(r0 + row) * DM + kt * 32 + aq * 8;
        const f32x4 v0 = *(const f32x4*)(src);
        const f32x4 v1 = *(const f32x4*)(src + 4);
#pragma unroll
        for (int i = 0; i < 4; i++) { fv[i] = v0[i]; fv[4 + i] = v1[i]; }
      } else {
        const int rr = r0 + row; const int bb = rr >> 11; const int ll = rr & 2047;
        const int cc = kt * 32 + aq * 8; const int h = cc >> 6; const int d = cc & 63;
        const size_t off = (((size_t)bb * NH + h) * SEQ + ll) * HD + d;
        const f32x4 a0 = *(const f32x4*)((const float*)Aptr + off);
        const f32x4 a1 = *(const f32x4*)((const float*)Aptr + off + 4);
        const f32x4 b0 = *(const f32x4*)((const float*)A2ptr + off);
        const f32x4 b1 = *(const f32x4*)((const float*)A2ptr + off + 4);
#pragma unroll
        for (int i = 0; i < 4; i++) { fv[i] = a0[i] + b0[i]; fv[4 + i] = a1[i] + b1[i]; }
      }
      bf16x8 av;
#pragma unroll
      for (int i = 0; i < 8; i++) av[i] = (__bf16)fv[i];
      *(bf16x8*)&Alds[row][aq * 8] = av;
    }
    {
      const __bf16* bsrc = Bt + (size_t)(c0 + br) * DM + kt * 32 + bh * 16;
      bf16x8 v0 = *(const bf16x8*)bsrc;
      bf16x8 v1 = *(const bf16x8*)(bsrc + 8);
      *(bf16x8*)&Blds[br][bh * 16] = v0;
      *(bf16x8*)&Blds[br][bh * 16 + 8] = v1;
    }
    __syncthreads();
    bf16x8 af[4], bfr[4];
#pragma unroll
    for (int m = 0; m < 4; m++)
      af[m] = *(const bf16x8*)&Alds[wm * 64 + m * 16 + (l & 15)][(l >> 4) * 8];
#pragma unroll
    for (int n = 0; n < 4; n++)
      bfr[n] = *(const bf16x8*)&Blds[wn * 64 + n * 16 + (l & 15)][(l >> 4) * 8];
#pragma unroll
    for (int m = 0; m < 4; m++)
#pragma unroll
      for (int n = 0; n < 4; n++) acc[m][n] = mfma16x16(af[m], bfr[n], acc[m][n]);
    __syncthreads();
  }

  // Epilogue. C layout (16x16x32): col = l&15, row = (l>>4)*4 + r  [guide-verified]
  const int ccol = l & 15;
  const int crb = (l >> 4) * 4;
#pragma unroll
  for (int n = 0; n < 4; n++) {
    const int col = c0 + wn * 64 + n * 16 + ccol;
    const float bv = bias[col];
#pragma unroll
    for (int m = 0; m < 4; m++) {
      const int row = r0 + wm * 64 + m * 16 + crb;
      f32x4 v = acc[m][n];
#pragma unroll
      for (int r = 0; r < 4; r++) v[r] += bv;
      if constexpr (OMODE == 2) {
        float* O = (float*)Out;
#pragma unroll
        for (int r = 0; r < 4; r++) O[(size_t)(row + r) * DM + col] = v[r];
      } else if constexpr (OMODE == 0) {
        __bf16* O = (__bf16*)Out;
        const int h = col >> 6, d = col & 63;
#pragma unroll
        for (int r = 0; r < 4; r++) {
          const int rr = row + r; const int bb = rr >> 11; const int ll = rr & 2047;
          O[(((size_t)bb * NH + h) * SEQ + ll) * HD + d] = (__bf16)v[r];
        }
      } else {  // OMODE 1: V^T [b,h,d,l], 4 consecutive l per lane -> 8B store
        __bf16* O = (__bf16*)Out;
        const int h = col >> 6, d = col & 63;
        const int bb = row >> 11, ll = row & 2047;
        bf16x4 pk;
#pragma unroll
        for (int r = 0; r < 4; r++) pk[r] = (__bf16)v[r];
        *(bf16x4*)&O[(((size_t)bb * NH + h) * HD + d) * SEQ + ll] = pk;
      }
    }
  }
}

// ---------------- Attention with softmax over HEADS ------------------------
// E' = mfma(K, Q^T): C layout row = k_local = (r&3)+8*(r>>2)+4*hi, col = q_local = l&31
__device__ __forceinline__ void process_head(const float (&pp)[16], const float (&rd)[16],
                                             int hi, int lq, int k0,
                                             const __bf16* __restrict__ vbase,
                                             f32x16& x0, f32x16& x1) {
  unsigned u[8];
#pragma unroll
  for (int j = 0; j < 8; j++) {
    const float a = pp[2 * j] * rd[2 * j];
    const float b = pp[2 * j + 1] * rd[2 * j + 1];
    u[j] = pkbf(a, b);
  }
  unsigned t[8];
#pragma unroll
  for (int j = 0; j < 8; j++) t[j] = (unsigned)__shfl_xor((int)u[j], 32, 64);
  const unsigned w0 = hi ? t[2] : u[0];
  const unsigned w1 = hi ? t[3] : u[1];
  const unsigned w2 = hi ? u[2] : t[0];
  const unsigned w3 = hi ? u[3] : t[1];
  const unsigned w4 = hi ? t[6] : u[4];
  const unsigned w5 = hi ? t[7] : u[5];
  const unsigned w6 = hi ? u[6] : t[4];
  const unsigned w7 = hi ? u[7] : t[5];
  const uint4v s0v = {w0, w1, w2, w3};
  const uint4v s1v = {w4, w5, w6, w7};
  const bf16x8 pa0 = __builtin_bit_cast(bf16x8, s0v);
  const bf16x8 pa1 = __builtin_bit_cast(bf16x8, s1v);
  const __bf16* vp = vbase + (size_t)lq * SEQ + k0 + hi * 8;
  bf16x8 vf;
  vf = *(const bf16x8*)(vp);                     x0 = mfma32x32(pa0, vf, x0);
  vf = *(const bf16x8*)(vp + 16);                x0 = mfma32x32(pa1, vf, x0);
  vf = *(const bf16x8*)(vp + (size_t)32 * SEQ);  x1 = mfma32x32(pa0, vf, x1);
  vf = *(const bf16x8*)(vp + (size_t)32 * SEQ + 16); x1 = mfma32x32(pa1, vf, x1);
}

__global__ __launch_bounds__(512, 2)
void attn_kernel(const __bf16* __restrict__ Qh, const __bf16* __restrict__ Kh,
                 const __bf16* __restrict__ Vt, const int* __restrict__ mask,
                 float* __restrict__ Xp) {
  __shared__ float part[8 * 64 * 16];  // [wave][lane][reg] partial exp-sums
  __shared__ float Dbuf[1024];         // per-(lane,reg) denominators
  __shared__ float biasl[32 * 34];     // mask bias tile [q][k], pad 34
  const int tid = threadIdx.x;
  const int l = tid & 63;
  const int w = tid >> 6;
  const int lq = l & 31;
  const int hi = l >> 5;
  const int qt = blockIdx.x, b = blockIdx.y, c = blockIdx.z;
  const int q0 = qt * 32;
  const int h0 = w * 2;

  // Preload Q as B-fragments: lane holds Q[b,h,q0+lq, ch*16+hi*8 .. +7]
  bf16x8 qf[2][4];
#pragma unroll
  for (int hh = 0; hh < 2; hh++) {
    const __bf16* qp = Qh + (((size_t)b * NH + h0 + hh) * SEQ + q0 + lq) * HD + hi * 8;
#pragma unroll
    for (int ch = 0; ch < 4; ch++) qf[hh][ch] = *(const bf16x8*)(qp + ch * 16);
  }
  f32x16 xacc[2][2];
#pragma unroll
  for (int i = 0; i < 2; i++)
#pragma unroll
    for (int j = 0; j < 2; j++) xacc[i][j] = zero16();

  const __bf16* kbase0 = Kh + ((size_t)b * NH + h0) * SEQ * HD;
  const __bf16* kbase1 = Kh + ((size_t)b * NH + h0 + 1) * SEQ * HD;
  const __bf16* vbase0 = Vt + ((size_t)b * NH + h0) * HD * SEQ;
  const __bf16* vbase1 = Vt + ((size_t)b * NH + h0 + 1) * HD * SEQ;

  for (int kt = 0; kt < 32; kt++) {
    const int k0 = c * 1024 + kt * 32;
    {  // stage mask -> additive bias tile (coalesced)
      const int qq = tid >> 4;
      const int kk = (tid & 15) * 2;
      const int* mp = mask + ((size_t)b * SEQ + q0 + qq) * SEQ + k0 + kk;
      const int m0 = mp[0], m1 = mp[1];
      biasl[qq * 34 + kk] = m0 ? 0.0f : -1e10f;
      biasl[qq * 34 + kk + 1] = m1 ? 0.0f : -1e10f;
    }
    __syncthreads();  // bias ready; Dbuf free for rewrite

    f32x16 e0 = zero16(), e1 = zero16();
#pragma unroll
    for (int ch = 0; ch < 4; ch++) {
      const bf16x8 kf = *(const bf16x8*)(kbase0 + ((size_t)(k0 + lq)) * HD + ch * 16 + hi * 8);
      e0 = mfma32x32(kf, qf[0][ch], e0);
    }
#pragma unroll
    for (int ch = 0; ch < 4; ch++) {
      const bf16x8 kf = *(const bf16x8*)(kbase1 + ((size_t)(k0 + lq)) * HD + ch * 16 + hi * 8);
      e1 = mfma32x32(kf, qf[1][ch], e1);
    }
    float p0[16], p1[16], s4[16];
#pragma unroll
    for (int r = 0; r < 16; r++) {
      const int crow = (r & 3) + 8 * (r >> 2) + 4 * hi;
      const float bv = biasl[lq * 34 + crow];
      const float a0 = fmaf(e0[r], 0.125f, bv);  // /sqrt(64) + mask bias (exact)
      const float a1 = fmaf(e1[r], 0.125f, bv);
      p0[r] = __expf(a0);
      p1[r] = __expf(a1);
      s4[r] = p0[r] + p1[r];
    }
    {
      float* pw = &part[(unsigned)((w << 6) | l) * 16];
#pragma unroll
      for (int i = 0; i < 4; i++) {
        f32x4 v;
#pragma unroll
        for (int j = 0; j < 4; j++) v[j] = s4[4 * i + j];
        *(f32x4*)(pw + 4 * i) = v;
      }
    }
    __syncthreads();
    {  // cross-wave reduce over 8 waves (16 heads) -> denominators
      const int p2 = tid * 2;
      float da = 0.0f, db = 0.0f;
#pragma unroll
      for (int w2 = 0; w2 < 8; w2++) {
        da += part[w2 * 1024 + p2];
        db += part[w2 * 1024 + p2 + 1];
      }
      Dbuf[p2] = da;
      Dbuf[p2 + 1] = db;
    }
    __syncthreads();
    float rd[16];
#pragma unroll
    for (int i = 0; i < 4; i++) {
      const f32x4 dv = *(const f32x4*)&Dbuf[l * 16 + i * 4];
#pragma unroll
      for (int j = 0; j < 4; j++) rd[4 * i + j] = __builtin_amdgcn_rcpf(dv[j]);
    }
    process_head(p0, rd, hi, lq, k0, vbase0, xacc[0][0], xacc[0][1]);
    process_head(p1, rd, hi, lq, k0, vbase1, xacc[1][0], xacc[1][1]);
  }

  // Write partial X: Xp[c][b][h][q][d], fp32
#pragma unroll
  for (int hh = 0; hh < 2; hh++) {
    float* xo = Xp + (size_t)c * ((size_t)NB * NH * SEQ * HD) +
                (((size_t)b * NH + h0 + hh) * SEQ + q0) * HD;
#pragma unroll
    for (int dt = 0; dt < 2; dt++) {
#pragma unroll
      for (int r = 0; r < 16; r++) {
        const int crow = (r & 3) + 8 * (r >> 2) + 4 * hi;
        xo[(size_t)crow * HD + dt * 32 + lq] = xacc[hh][dt][r];
      }
    }
  }
}

// ---------------------------------------------------------------------------
extern "C" void kernel_launch(void* const* d_in, const int* in_sizes, int n_in,
                              void* d_out, int out_size, void* d_ws, size_t ws_size,
                              hipStream_t stream) {
  const float* q = (const float*)d_in[0];
  const float* k = (const float*)d_in[1];
  const float* v = (const float*)d_in[2];
  const int* msk = (const int*)d_in[3];
  const float* Wq = (const float*)d_in[4];
  const float* bq = (const float*)d_in[5];
  const float* Wk = (const float*)d_in[6];
  const float* bk = (const float*)d_in[7];
  const float* Wv = (const float*)d_in[8];
  const float* bv = (const float*)d_in[9];
  const float* Wo = (const float*)d_in[10];
  const float* bo = (const float*)d_in[11];

  char* ws = (char*)d_ws;
  const size_t MB = 1024 * 1024;
  if (ws_size < 64 * MB) return;  // visible failure rather than OOB
  __bf16* Wt = (__bf16*)(ws);             // 4 x 1M bf16 (8 MB)
  __bf16* Qh = (__bf16*)(ws + 8 * MB);    // [b,h,l,d] 8 MB
  __bf16* Kh = (__bf16*)(ws + 16 * MB);   // [b,h,l,d] 8 MB
  __bf16* Vt = (__bf16*)(ws + 24 * MB);   // [b,h,d,l] 8 MB
  float* Xp = (float*)(ws + 32 * MB);     // 2 chunks x 16 MB fp32
  const size_t XCH = (size_t)NB * NH * SEQ * HD;

  wconv_kernel<<<dim3(32, 32, 4), 256, 0, stream>>>(Wq, Wk, Wv, Wo, Wt);
  gemm_kernel<0, 0><<<dim3(32, 8), 256, 0, stream>>>(q, nullptr, Wt, bq, Qh);
  gemm_kernel<0, 0><<<dim3(32, 8), 256, 0, stream>>>(k, nullptr, Wt + (size_t)DM * DM, bk, Kh);
  gemm_kernel<0, 1><<<dim3(32, 8), 256, 0, stream>>>(v, nullptr, Wt + (size_t)2 * DM * DM, bv, Vt);
  attn_kernel<<<dim3(64, 2, 2), 512, 0, stream>>>(Qh, Kh, Vt, msk, Xp);
  gemm_kernel<1, 2><<<dim3(32, 8), 256, 0, stream>>>(Xp, Xp + XCH, Wt + (size_t)3 * DM * DM, bo, d_out);
}